// Round 12
// baseline (191.835 us; speedup 1.0000x reference)
//
#include <hip/hip_runtime.h>
#include <hip/hip_fp16.h>

// ConformalGCN: 2-layer GCN, N=100000, E=1600000 (+self loops).
// R11: gemm1 restructured for latency hiding: 8 rows/wave (2x uint4 stage,
//      8 acc chains -> ~60% per-wave VALU duty), grid 1563 = 2 chunks/wave,
//      24KB LDS -> 6 blocks/CU. R10 showed the old gemm1 at ~40us with 34%
//      duty serial load->compute cycles. csr_agg/gemm2/CSR build unchanged.

#define IN_F  128
#define HID_F 64
#define OUT_F 96
#define CHUNK 4096
#define MAXB  12288         // stage capacity (padded bucket size), 48 KiB
#define AGG_BLOCKS 4096
#define ONE_LO 0x00003C00u  // fp16 (1.0, 0.0)
#define ONE_HI 0x3C000000u  // fp16 (0.0, 1.0)

typedef _Float16 f16x2 __attribute__((ext_vector_type(2)));

__device__ __forceinline__ float2 unpack2(unsigned u) {
    __half2 h = *reinterpret_cast<__half2*>(&u);
    return __half22float2(h);
}
__device__ __forceinline__ unsigned f2h2(float lo, float hi) {
    __half2 h = __floats2half2_rn(lo, hi);
    return *reinterpret_cast<unsigned*>(&h);
}

#if defined(__has_builtin)
#if __has_builtin(__builtin_amdgcn_fdot2)
#define HAS_FDOT2 1
#endif
#endif
#ifndef HAS_FDOT2
#define HAS_FDOT2 0
#endif

__device__ __forceinline__ float fdot2u(unsigned a, unsigned b, float c) {
#if HAS_FDOT2
    return __builtin_amdgcn_fdot2(__builtin_bit_cast(f16x2, a),
                                  __builtin_bit_cast(f16x2, b), c, false);
#else
    float2 fa = unpack2(a), fb = unpack2(b);
    return fmaf(fa.y, fb.y, fmaf(fa.x, fb.x, c));
#endif
}

// zero the sentinel feature rows hs[n], hs2[n]
__global__ __launch_bounds__(64) void init_sentinel(unsigned* __restrict__ hs,
                                                    unsigned* __restrict__ hs2, int n) {
    int t = threadIdx.x;
    if (t < 32) {
        hs[(size_t)n * 32 + t] = 0u;
        hs2[(size_t)n * 32 + t] = 0u;
    }
}

// ---- pass 1a: per-chunk bucket histograms (bucket-major layout) ----
__global__ __launch_bounds__(256) void hist_chunks(const int* __restrict__ dst,
                                                   int* __restrict__ hist,
                                                   int E, int nbuck, int nchunk) {
    __shared__ int cnt[512];
    for (int i = threadIdx.x; i < nbuck; i += 256) cnt[i] = 0;
    __syncthreads();
    const int base = blockIdx.x * CHUNK;
    const int lim = min(base + CHUNK, E);
    for (int e = base + threadIdx.x; e < lim; e += 256)
        atomicAdd(&cnt[dst[e] >> 8], 1);
    __syncthreads();
    for (int b = threadIdx.x; b < nbuck; b += 256)
        hist[b * nchunk + blockIdx.x] = cnt[b];
}

// ---- hierarchical exclusive prefix sum (1024 elems/block) ----
__global__ __launch_bounds__(256) void scan_blocks(const int* __restrict__ in,
                                                   int* __restrict__ pre,
                                                   int* __restrict__ bsum, int m) {
    __shared__ int lds[256];
    const int t = threadIdx.x;
    const int base = blockIdx.x * 1024 + t * 4;
    int v0 = (base + 0 < m) ? in[base + 0] : 0;
    int v1 = (base + 1 < m) ? in[base + 1] : 0;
    int v2 = (base + 2 < m) ? in[base + 2] : 0;
    int v3 = (base + 3 < m) ? in[base + 3] : 0;
    int s = v0 + v1 + v2 + v3;
    lds[t] = s;
    __syncthreads();
    for (int off = 1; off < 256; off <<= 1) {
        int add = (t >= off) ? lds[t - off] : 0;
        __syncthreads();
        lds[t] += add;
        __syncthreads();
    }
    int e = lds[t] - s;
    if (base + 0 < m) pre[base + 0] = e;
    e += v0;
    if (base + 1 < m) pre[base + 1] = e;
    e += v1;
    if (base + 2 < m) pre[base + 2] = e;
    e += v2;
    if (base + 3 < m) pre[base + 3] = e;
    if (t == 255) bsum[blockIdx.x] = lds[255];
}

__global__ __launch_bounds__(256) void scan_bsums(const int* __restrict__ bsum,
                                                  int* __restrict__ boffs, int nb) {
    __shared__ int lds[256];
    const int t = threadIdx.x;
    int v = (t < nb) ? bsum[t] : 0;
    lds[t] = v;
    __syncthreads();
    for (int off = 1; off < 256; off <<= 1) {
        int add = (t >= off) ? lds[t - off] : 0;
        __syncthreads();
        lds[t] += add;
        __syncthreads();
    }
    boffs[t] = lds[t] - v;
}

// ---- pass 1b: partition edges into bucket-grouped runs, 4B records ----
__global__ __launch_bounds__(256) void partition(const int* __restrict__ src,
                                                 const int* __restrict__ dst,
                                                 const int* __restrict__ offs,
                                                 const int* __restrict__ boffs,
                                                 unsigned* __restrict__ part,
                                                 int E, int nbuck, int nchunk) {
    __shared__ int off[512];
    for (int b = threadIdx.x; b < nbuck; b += 256) {
        int idx = b * nchunk + blockIdx.x;
        off[b] = offs[idx] + boffs[idx >> 10];
    }
    __syncthreads();
    const int base = blockIdx.x * CHUNK;
    const int lim = min(base + CHUNK, E);
    for (int e = base + threadIdx.x; e < lim; e += 256) {
        int d = dst[e], s = src[e];
        int pos = atomicAdd(&off[d >> 8], 1);
        part[pos] = ((unsigned)s << 8) | (unsigned)(d & 255);
    }
}

// ---- pass 2: per-bucket padded CSR finalize ----
__global__ __launch_bounds__(256) void build_bucket(const unsigned* __restrict__ part,
                                                    const int* __restrict__ offs,
                                                    const int* __restrict__ boffs,
                                                    int* __restrict__ csr_src,
                                                    int4* __restrict__ nodetab,
                                                    float* __restrict__ dinv,
                                                    int n, int E, int nbuck, int nchunk) {
    __shared__ int cnt[256], sc[256], off[256];
    __shared__ int stage[MAXB];
    const int b = blockIdx.x;
    const int t = threadIdx.x;
    const int i0 = b * nchunk;
    const int bstart = offs[i0] + boffs[i0 >> 10];
    int bend = E;
    if (b + 1 < nbuck) {
        const int i1 = (b + 1) * nchunk;
        bend = offs[i1] + boffs[i1 >> 10];
    }
    const int bstart_pad = bstart + b * 4096;
    const int nodebase = b << 8;
    const int nnodes = min(256, n - nodebase);

    cnt[t] = 0;
    __syncthreads();
    for (int i = bstart + t; i < bend; i += 256)
        atomicAdd(&cnt[part[i] & 255u], 1);
    __syncthreads();
    const int deg = cnt[t];
    const int pdeg = (deg + 15) & ~15;
    sc[t] = pdeg;
    __syncthreads();
    for (int o = 1; o < 256; o <<= 1) {
        int add = (t >= o) ? sc[t - o] : 0;
        __syncthreads();
        sc[t] += add;
        __syncthreads();
    }
    const int pexcl = sc[t] - pdeg;
    const int psize = sc[255];
    if (t < nnodes) {
        float dv = rsqrtf((float)(deg + 1));   // +1 self loop
        nodetab[nodebase + t] = make_int4(bstart_pad + pexcl,
                                          bstart_pad + pexcl + pdeg,
                                          __float_as_int(dv), 0);
        dinv[nodebase + t] = dv;
    }
    off[t] = pexcl;
    __syncthreads();

    if (psize <= MAXB) {
        for (int i = t; i < psize; i += 256) stage[i] = n;   // sentinel fill
        __syncthreads();
        for (int i = bstart + t; i < bend; i += 256) {
            unsigned r = part[i];
            int pos = atomicAdd(&off[r & 255u], 1);
            stage[pos] = (int)(r >> 8);
        }
        __syncthreads();
        for (int i = t; i < psize; i += 256)
            csr_src[bstart_pad + i] = stage[i];
    } else {   // safety fallback
        for (int i = t; i < psize; i += 256) csr_src[bstart_pad + i] = n;
        __syncthreads();
        for (int i = bstart + t; i < bend; i += 256) {
            unsigned r = part[i];
            int pos = atomicAdd(&off[r & 255u], 1);
            csr_src[bstart_pad + pos] = (int)(r >> 8);
        }
    }
}

// hs[row] = fp16x2( dinv[row] * (x[row] @ W1) ).
// 8 rows per wave (2x uint4 broadcast stages, 8 acc chains): per k2 =
// 2 broadcast b128 + 1 full-wave b32 LDS for 8 dot2.  Grid sized for
// 2 chunks/wave; 24KB LDS -> 6 blocks/CU -> TLP covers load latency.
__global__ __launch_bounds__(256) void gemm1(const float* __restrict__ x,
                                             const float* __restrict__ W1,
                                             const float* __restrict__ dinv,
                                             unsigned* __restrict__ hs, int n) {
    __shared__ unsigned w2[64 * HID_F];     // 16 KiB [k2][col]
    __shared__ uint4 xs[4][2][64];          // 8 KiB, per-wave 2x4-row stages
    for (int t = threadIdx.x; t < 64 * HID_F; t += 256) {
        int k2 = t >> 6, col = t & 63;
        w2[t] = f2h2(W1[(2 * k2) * HID_F + col], W1[(2 * k2 + 1) * HID_F + col]);
    }
    __syncthreads();
    const int wave = threadIdx.x >> 6, lane = threadIdx.x & 63;
    const int noct = (n + 7) >> 3;
    for (int q = blockIdx.x * 4 + wave; q < noct; q += gridDim.x * 4) {
        const int r0 = q * 8;
        const float* xp = x + (size_t)r0 * IN_F + lane * 2;
        float2 v0 = *(const float2*)(xp);                 // r0 always valid
        float2 v1 = (r0 + 1 < n) ? *(const float2*)(xp + 1 * IN_F) : make_float2(0.f, 0.f);
        float2 v2 = (r0 + 2 < n) ? *(const float2*)(xp + 2 * IN_F) : make_float2(0.f, 0.f);
        float2 v3 = (r0 + 3 < n) ? *(const float2*)(xp + 3 * IN_F) : make_float2(0.f, 0.f);
        float2 v4 = (r0 + 4 < n) ? *(const float2*)(xp + 4 * IN_F) : make_float2(0.f, 0.f);
        float2 v5 = (r0 + 5 < n) ? *(const float2*)(xp + 5 * IN_F) : make_float2(0.f, 0.f);
        float2 v6 = (r0 + 6 < n) ? *(const float2*)(xp + 6 * IN_F) : make_float2(0.f, 0.f);
        float2 v7 = (r0 + 7 < n) ? *(const float2*)(xp + 7 * IN_F) : make_float2(0.f, 0.f);
        uint4 pa, pb;
        pa.x = f2h2(v0.x, v0.y); pa.y = f2h2(v1.x, v1.y);
        pa.z = f2h2(v2.x, v2.y); pa.w = f2h2(v3.x, v3.y);
        pb.x = f2h2(v4.x, v4.y); pb.y = f2h2(v5.x, v5.y);
        pb.z = f2h2(v6.x, v6.y); pb.w = f2h2(v7.x, v7.y);
        xs[wave][0][lane] = pa;
        xs[wave][1][lane] = pb;
        float a0 = 0.f, a1 = 0.f, a2 = 0.f, a3 = 0.f;
        float a4 = 0.f, a5 = 0.f, a6 = 0.f, a7 = 0.f;
#pragma unroll 8
        for (int k2 = 0; k2 < 64; ++k2) {
            uint4 xa = xs[wave][0][k2];             // broadcast b128
            uint4 xb = xs[wave][1][k2];             // broadcast b128
            unsigned wv = w2[k2 * 64 + lane];       // full-wave b32
            a0 = fdot2u(xa.x, wv, a0);
            a1 = fdot2u(xa.y, wv, a1);
            a2 = fdot2u(xa.z, wv, a2);
            a3 = fdot2u(xa.w, wv, a3);
            a4 = fdot2u(xb.x, wv, a4);
            a5 = fdot2u(xb.y, wv, a5);
            a6 = fdot2u(xb.z, wv, a6);
            a7 = fdot2u(xb.w, wv, a7);
        }
        a0 *= dinv[r0];
        a1 *= (r0 + 1 < n) ? dinv[r0 + 1] : 0.f;
        a2 *= (r0 + 2 < n) ? dinv[r0 + 2] : 0.f;
        a3 *= (r0 + 3 < n) ? dinv[r0 + 3] : 0.f;
        a4 *= (r0 + 4 < n) ? dinv[r0 + 4] : 0.f;
        a5 *= (r0 + 5 < n) ? dinv[r0 + 5] : 0.f;
        a6 *= (r0 + 6 < n) ? dinv[r0 + 6] : 0.f;
        a7 *= (r0 + 7 < n) ? dinv[r0 + 7] : 0.f;
        float o0 = __shfl_xor(a0, 1), o1 = __shfl_xor(a1, 1);
        float o2 = __shfl_xor(a2, 1), o3 = __shfl_xor(a3, 1);
        float o4 = __shfl_xor(a4, 1), o5 = __shfl_xor(a5, 1);
        float o6 = __shfl_xor(a6, 1), o7 = __shfl_xor(a7, 1);
        if (!(lane & 1)) {
            int wd = lane >> 1;
            hs[(size_t)r0 * 32 + wd] = f2h2(a0, o0);
            if (r0 + 1 < n) hs[(size_t)(r0 + 1) * 32 + wd] = f2h2(a1, o1);
            if (r0 + 2 < n) hs[(size_t)(r0 + 2) * 32 + wd] = f2h2(a2, o2);
            if (r0 + 3 < n) hs[(size_t)(r0 + 3) * 32 + wd] = f2h2(a3, o3);
            if (r0 + 4 < n) hs[(size_t)(r0 + 4) * 32 + wd] = f2h2(a4, o4);
            if (r0 + 5 < n) hs[(size_t)(r0 + 5) * 32 + wd] = f2h2(a5, o5);
            if (r0 + 6 < n) hs[(size_t)(r0 + 6) * 32 + wd] = f2h2(a6, o6);
            if (r0 + 7 < n) hs[(size_t)(r0 + 7) * 32 + wd] = f2h2(a7, o7);
        }
    }
}

// Grid-stride; each wave owns TWO consecutive nodes with interleaved
// branchless gather chains.  Rows padded to %16.  fdot2 lane-extract accum.
#define ACC2(u, slo, shi) { slo = fdot2u(u, ONE_LO, slo); shi = fdot2u(u, ONE_HI, shi); }
template <int LAYER>
__global__ __launch_bounds__(256) void csr_agg(const int4* __restrict__ nodetab,
                                               const int* __restrict__ csr_src,
                                               const unsigned* __restrict__ hs,
                                               const float* __restrict__ bias,
                                               unsigned* __restrict__ hout, int n) {
    const int lane = threadIdx.x & 63;
    const int g = lane >> 4;          // edge slot 0..3
    const int w = lane & 15;          // feats 4w..4w+3
    const unsigned* __restrict__ hw = hs + 2 * w;
    const int STR = gridDim.x * 8;
    const int SENT = n;

    int nodeA = (blockIdx.x * 4 + (threadIdx.x >> 6)) * 2;
    if (nodeA >= n) return;
    int4 ntA = nodetab[nodeA];
    bool hasB = nodeA + 1 < n;
    int4 ntB = hasB ? nodetab[nodeA + 1] : make_int4(0, 0, 0, 0);

    for (;;) {
        const int nxt = nodeA + STR;
        const bool more = nxt < n;
        int4 ntA_n, ntB_n;
        bool hasB_n = false;
        if (more) {
            ntA_n = nodetab[nxt];
            hasB_n = nxt + 1 < n;
            if (hasB_n) ntB_n = nodetab[nxt + 1];
        }

        int pA = ntA.x;
        const int endA = ntA.y;
        const float dnA = __int_as_float(ntA.z);
        int pB = hasB ? ntB.x : 0;
        const int endB = hasB ? ntB.y : 0;
        const float dnB = hasB ? __int_as_float(ntB.z) : 0.f;

        float aA0 = 0.f, aA1 = 0.f, aA2 = 0.f, aA3 = 0.f;
        float cA0 = 0.f, cA1 = 0.f, cA2 = 0.f, cA3 = 0.f;
        float aB0 = 0.f, aB1 = 0.f, aB2 = 0.f, aB3 = 0.f;
        float cB0 = 0.f, cB1 = 0.f, cB2 = 0.f, cB3 = 0.f;
        if (g == 0) {                                      // self loops, once
            uint2 suA = *(const uint2*)(hw + (size_t)nodeA * 32);
            ACC2(suA.x, aA0, aA1);
            ACC2(suA.y, aA2, aA3);
            if (hasB) {
                uint2 suB = *(const uint2*)(hw + (size_t)(nodeA + 1) * 32);
                ACC2(suB.x, aB0, aB1);
                ACC2(suB.y, aB2, aB3);
            }
        }
        while (pA < endA || pB < endB) {
            int4 ivA = (pA < endA) ? *(const int4*)&csr_src[pA + 4 * g]
                                   : make_int4(SENT, SENT, SENT, SENT);
            int4 ivB = (pB < endB) ? *(const int4*)&csr_src[pB + 4 * g]
                                   : make_int4(SENT, SENT, SENT, SENT);
            uint2 uA0 = *(const uint2*)(hw + (size_t)ivA.x * 32);
            uint2 uA1 = *(const uint2*)(hw + (size_t)ivA.y * 32);
            uint2 uA2 = *(const uint2*)(hw + (size_t)ivA.z * 32);
            uint2 uA3 = *(const uint2*)(hw + (size_t)ivA.w * 32);
            uint2 uB0 = *(const uint2*)(hw + (size_t)ivB.x * 32);
            uint2 uB1 = *(const uint2*)(hw + (size_t)ivB.y * 32);
            uint2 uB2 = *(const uint2*)(hw + (size_t)ivB.z * 32);
            uint2 uB3 = *(const uint2*)(hw + (size_t)ivB.w * 32);
            ACC2(uA0.x, aA0, aA1); ACC2(uA0.y, aA2, aA3);
            ACC2(uA1.x, cA0, cA1); ACC2(uA1.y, cA2, cA3);
            ACC2(uA2.x, aA0, aA1); ACC2(uA2.y, aA2, aA3);
            ACC2(uA3.x, cA0, cA1); ACC2(uA3.y, cA2, cA3);
            ACC2(uB0.x, aB0, aB1); ACC2(uB0.y, aB2, aB3);
            ACC2(uB1.x, cB0, cB1); ACC2(uB1.y, cB2, cB3);
            ACC2(uB2.x, aB0, aB1); ACC2(uB2.y, aB2, aB3);
            ACC2(uB3.x, cB0, cB1); ACC2(uB3.y, cB2, cB3);
            pA += 16; pB += 16;
        }
        aA0 += cA0; aA1 += cA1; aA2 += cA2; aA3 += cA3;
        aB0 += cB0; aB1 += cB1; aB2 += cB2; aB3 += cB3;
        aA0 += __shfl_xor(aA0, 16); aA0 += __shfl_xor(aA0, 32);
        aA1 += __shfl_xor(aA1, 16); aA1 += __shfl_xor(aA1, 32);
        aA2 += __shfl_xor(aA2, 16); aA2 += __shfl_xor(aA2, 32);
        aA3 += __shfl_xor(aA3, 16); aA3 += __shfl_xor(aA3, 32);
        aB0 += __shfl_xor(aB0, 16); aB0 += __shfl_xor(aB0, 32);
        aB1 += __shfl_xor(aB1, 16); aB1 += __shfl_xor(aB1, 32);
        aB2 += __shfl_xor(aB2, 16); aB2 += __shfl_xor(aB2, 32);
        aB3 += __shfl_xor(aB3, 16); aB3 += __shfl_xor(aB3, 32);

        if (g == 0) {
            float o0, o1, o2, o3;
            if (LAYER == 1) {
                float4 bb = *(const float4*)(bias + 4 * w);
                o0 = fmaxf(fmaf(dnA, aA0, bb.x), 0.f) * dnA;
                o1 = fmaxf(fmaf(dnA, aA1, bb.y), 0.f) * dnA;
                o2 = fmaxf(fmaf(dnA, aA2, bb.z), 0.f) * dnA;
                o3 = fmaxf(fmaf(dnA, aA3, bb.w), 0.f) * dnA;
            } else {
                o0 = dnA * aA0; o1 = dnA * aA1; o2 = dnA * aA2; o3 = dnA * aA3;
            }
            uint2 ov;
            ov.x = f2h2(o0, o1);
            ov.y = f2h2(o2, o3);
            *(uint2*)(hout + (size_t)nodeA * 32 + 2 * w) = ov;
            if (hasB) {
                if (LAYER == 1) {
                    float4 bb = *(const float4*)(bias + 4 * w);
                    o0 = fmaxf(fmaf(dnB, aB0, bb.x), 0.f) * dnB;
                    o1 = fmaxf(fmaf(dnB, aB1, bb.y), 0.f) * dnB;
                    o2 = fmaxf(fmaf(dnB, aB2, bb.z), 0.f) * dnB;
                    o3 = fmaxf(fmaf(dnB, aB3, bb.w), 0.f) * dnB;
                } else {
                    o0 = dnB * aB0; o1 = dnB * aB1; o2 = dnB * aB2; o3 = dnB * aB3;
                }
                ov.x = f2h2(o0, o1);
                ov.y = f2h2(o2, o3);
                *(uint2*)(hout + (size_t)(nodeA + 1) * 32 + 2 * w) = ov;
            }
        }
        if (!more) break;
        nodeA = nxt;
        ntA = ntA_n;
        hasB = hasB_n;
        ntB = ntB_n;
    }
}

// out[n][96] = a2[n][64] @ W2[64][96] + b2.  fp16 tile (+1 pad) in LDS,
// 4 outputs/thread.
__global__ __launch_bounds__(256) void gemm2(const unsigned* __restrict__ a2h,
                                             const float* __restrict__ W2,
                                             const float* __restrict__ b2,
                                             float* __restrict__ out, int n) {
    __shared__ unsigned w2[32 * OUT_F];     // [k2][j], 12 KiB
    __shared__ float bs[OUT_F];
    __shared__ unsigned tile[256 * 33];     // +1 word pad per row
    for (int t = threadIdx.x; t < 32 * OUT_F; t += 256) {
        int k2 = t / OUT_F, j = t - k2 * OUT_F;
        w2[t] = f2h2(W2[(2 * k2) * OUT_F + j], W2[(2 * k2 + 1) * OUT_F + j]);
    }
    for (int t = threadIdx.x; t < OUT_F; t += 256) bs[t] = b2[t];
    const int base = blockIdx.x * 256;
    const int rows = min(256, n - base);
    const uint4* srcv = (const uint4*)(a2h + (size_t)base * 32);
    const int nvec = rows * 8;
    for (int t = threadIdx.x; t < nvec; t += 256) {
        uint4 v = srcv[t];
        int r = t >> 3, w0 = (t & 7) * 4;
        unsigned* d = &tile[r * 33 + w0];
        d[0] = v.x; d[1] = v.y; d[2] = v.z; d[3] = v.w;
    }
    __syncthreads();
    const int total = rows * 24;
    for (int idx = threadIdx.x; idx < total; idx += 256) {
        int r = idx / 24, jq = idx - r * 24, j = jq * 4;
        float4 bb = *(const float4*)&bs[j];
        float acc0 = bb.x, acc1 = bb.y, acc2 = bb.z, acc3 = bb.w;
        const unsigned* tr = &tile[r * 33];
#pragma unroll
        for (int k2 = 0; k2 < 32; ++k2) {
            unsigned tv = tr[k2];
            uint4 wv = *(const uint4*)&w2[k2 * OUT_F + j];
            acc0 = fdot2u(tv, wv.x, acc0);
            acc1 = fdot2u(tv, wv.y, acc1);
            acc2 = fdot2u(tv, wv.z, acc2);
            acc3 = fdot2u(tv, wv.w, acc3);
        }
        *(float4*)(out + (size_t)(base + r) * OUT_F + j) =
            make_float4(acc0, acc1, acc2, acc3);
    }
}

extern "C" void kernel_launch(void* const* d_in, const int* in_sizes, int n_in,
                              void* d_out, int out_size, void* d_ws, size_t ws_size,
                              hipStream_t stream) {
    const float* x  = (const float*)d_in[0];
    const int*   ei = (const int*)d_in[1];
    const float* W1 = (const float*)d_in[2];
    const float* b1 = (const float*)d_in[3];
    const float* W2 = (const float*)d_in[4];
    const float* b2 = (const float*)d_in[5];
    float* out = (float*)d_out;

    const int n = in_sizes[0] / IN_F;          // 100000
    const int E = in_sizes[1] / 2;             // 1600000
    const int* src = ei;
    const int* dst = ei + E;
    const int nbuck  = (n + 255) >> 8;         // 391
    const int nchunk = (E + CHUNK - 1) / CHUNK;// 391
    const int M = nbuck * nchunk;              // 152881
    const int NBS = (M + 1023) / 1024;
    const int ntile = (n + 255) / 256;         // 391
    const int noct = (n + 7) / 8;              // 12500
    const int g1blocks = (noct + 7) / 8;       // 2 chunks/wave -> 1563

    char* ws = (char*)d_ws;
    size_t off = 0;
    auto alloc = [&](size_t bytes) { void* p = ws + off; off = (off + bytes + 255) & ~(size_t)255; return p; };
    int*      hist    = (int*)alloc((size_t)M * 4);
    int*      offs    = (int*)alloc((size_t)M * 4);
    int*      bsum    = (int*)alloc(256 * 4);
    int*      boffs   = (int*)alloc(256 * 4);
    unsigned* part    = (unsigned*)alloc((size_t)E * 4);
    int*      csr_src = (int*)alloc(((size_t)E + (size_t)nbuck * 4096 + 64) * 4);
    int4*     nodetab = (int4*)alloc((size_t)n * 16);
    float*    dinv    = (float*)alloc((size_t)n * 4);
    unsigned* hs      = (unsigned*)alloc((size_t)(n + 1) * 32 * 4);
    unsigned* hs2     = (unsigned*)alloc((size_t)(n + 1) * 32 * 4);
    unsigned* a2h     = (unsigned*)alloc((size_t)n * 32 * 4);

    // CSR build: histogram -> scan -> partition -> per-bucket padded finalize
    init_sentinel<<<1, 64, 0, stream>>>(hs, hs2, n);
    hist_chunks <<<nchunk, 256, 0, stream>>>(dst, hist, E, nbuck, nchunk);
    scan_blocks <<<NBS, 256, 0, stream>>>(hist, offs, bsum, M);
    scan_bsums  <<<1, 256, 0, stream>>>(bsum, boffs, NBS);
    partition   <<<nchunk, 256, 0, stream>>>(src, dst, offs, boffs, part, E, nbuck, nchunk);
    build_bucket<<<nbuck, 256, 0, stream>>>(part, offs, boffs, csr_src, nodetab, dinv,
                                            n, E, nbuck, nchunk);

    // network
    gemm1      <<<g1blocks, 256, 0, stream>>>(x, W1, dinv, hs, n);
    csr_agg<1> <<<AGG_BLOCKS, 256, 0, stream>>>(nodetab, csr_src, hs, b1, hs2, n);
    csr_agg<2> <<<AGG_BLOCKS, 256, 0, stream>>>(nodetab, csr_src, hs2, NULL, a2h, n);
    gemm2      <<<ntile, 256, 0, stream>>>(a2h, W2, b2, out, n);
}